// Round 11
// baseline (88.552 us; speedup 1.0000x reference)
//
#include <hip/hip_runtime.h>
#include <hip/hip_bf16.h>

// Problem: T=2048, B=32, H=512
//   scores[b,t] = sum_o v[o] * tanh( hb[b,o] + sum_h enc[t,b,h] * W2[o,h] )
//   out[b,0,t]  = softmax_t(scores[b,:])
//
// HARD-WON RULES (R2..R10 post-mortems):
//  - WRITE_SIZE >> 2MB == scratch spill. Rotating/indexed register arrays and
//    __launch_bounds__ min-waves>=4 trigger it. Keep staging fully static.
//  - R8 structure (B via global_load_lds from pre-swizzled image, A reg-staged
//    dist-2 ping-pong) + R9 XCD remap = verified good (92us, 0 conflicts, 0 spill).
//  - R10 residual: __syncthreads() == vmcnt(0) drain of the 12 fresh prefetch
//    loads every step. R11: counted vmcnt + raw s_barrier (T4) + setprio (T5).

#define TT 2048
#define BB 32
#define HH 512

typedef __attribute__((ext_vector_type(8))) short bf16x8;
typedef __attribute__((ext_vector_type(4))) float f32x4;

#define VMWAIT_(N) asm volatile("s_waitcnt vmcnt(" #N ")" ::: "memory")
#define VMWAIT(N) VMWAIT_(N)
#define LGKM0_BAR() do { asm volatile("s_waitcnt lgkmcnt(0)" ::: "memory"); \
                         __builtin_amdgcn_s_barrier(); } while (0)

static __device__ __forceinline__ unsigned cvt2(float a, float b) {
    union { __hip_bfloat162 h; unsigned u; } cv;
    cv.h = __float22bfloat162_rn(make_float2(a, b));   // v_cvt_pk_bf16_f32
    return cv.u;
}

static __device__ __forceinline__ unsigned short f2bf(float f) {
    unsigned int u = __float_as_uint(f);
    unsigned int r = (u + 0x7FFFu + ((u >> 16) & 1u)) >> 16;  // RNE
    return (unsigned short)r;
}

// tanh(x) = 1 - 2/(1+e^{2x});  inf-safe at both ends.
static __device__ __forceinline__ float fast_tanh(float x) {
    float e = __expf(2.0f * x);
    return 1.0f - 2.0f * __builtin_amdgcn_rcpf(1.0f + e);
}

static __device__ __forceinline__ void gload_lds16(const void* g, void* l) {
    __builtin_amdgcn_global_load_lds(
        (const __attribute__((address_space(1))) unsigned int*)g,
        (__attribute__((address_space(3))) unsigned int*)l, 16, 0, 0);
}

// ---- Kernel 1: pack W2 (= W_attn[:, 512:1024]) into the swizzled LDS image.
// idx = nt*65536 + ks*8192 + j*64 + c (shorts); element = W2[nt*128+j][ks*64 + (c ^ ((j&7)<<3))]
__global__ void pack_w2_kernel(const float* __restrict__ W, short* __restrict__ W2p) {
    int idx = blockIdx.x * 256 + threadIdx.x;      // 262144 total
    int nt = idx >> 16;
    int ks = (idx >> 13) & 7;
    int s  = idx & 8191;
    int j  = s >> 6;
    int c  = s & 63;
    int kk = c ^ ((j & 7) << 3);
    int o  = nt * 128 + j;
    int k  = ks * 64 + kk;
    W2p[idx] = (short)f2bf(W[o * 1024 + 512 + k]);
}

// ---- Kernel 2: hb[b][o] = b_attn[o] + sum_h hidden[b,h] * W_attn[o,h]
__global__ void hb_kernel(const float* __restrict__ hidden, const float* __restrict__ W,
                          const float* __restrict__ b_attn, float* __restrict__ hb) {
    __shared__ float hrow[512];
    int b = blockIdx.x >> 1;
    int o = ((blockIdx.x & 1) << 8) + threadIdx.x;
    for (int h = threadIdx.x; h < 512; h += 256) hrow[h] = hidden[b * 512 + h];
    __syncthreads();
    const float4* wr = reinterpret_cast<const float4*>(W + (size_t)o * 1024);
    const float4* hr = reinterpret_cast<const float4*>(hrow);
    float acc = b_attn[o];
#pragma unroll 8
    for (int i = 0; i < 128; ++i) {
        float4 w = wr[i], h4 = hr[i];
        acc += w.x * h4.x + w.y * h4.y + w.z * h4.z + w.w * h4.w;
    }
    hb[b * 512 + o] = acc;
}

// ---- Kernel 3: 128x128-tile double-buffered GEMM + fused tanh/v-dot epilogue.
// Grid: 2048 blocks, XCD remap w=(bid&7)*256+(bid>>3); nt=w&3, mtile=w>>2.
// 256 threads = 4 waves (wr x wc = 2x2), each wave computes 64x64.
// K = 512 in 8 steps of 64. A: dist-2 reg prefetch (rA0/rA1) -> cvt -> ds_write.
// B: global_load_lds from pre-swizzled W2p, 1-ahead.
// R11: raw barriers (lgkmcnt(0) only) + counted vmcnt gate before COMPUTE so
// the 12 per-step prefetch loads stay in flight ACROSS the barrier (T4), and
// s_setprio(1) around the MFMA cluster (T5).
__global__ __launch_bounds__(256, 2) void attn_main_kernel(
    const float* __restrict__ enc, const short* __restrict__ W2p,
    const float* __restrict__ hb, const float* __restrict__ v,
    float* __restrict__ scores_part)
{
    __shared__ short As[2][128 * 64];   // 16KB x2, swizzled: col c2 = c ^ ((r&7)<<3)
    __shared__ short Bs[2][128 * 64];   // 16KB x2, image pre-swizzled by pack kernel
    __shared__ float s_red[2][128];

    const int tid = threadIdx.x;
    const int bid = blockIdx.x;
    const int w = (bid & 7) * 256 + (bid >> 3);  // XCD-contiguous work id (bijective)
    const int nt = w & 3;                // N-tile (128 o-cols)
    const int mtile = w >> 2;            // 512 M-tiles
    const int b = mtile >> 4;            // batch
    const int t0 = (mtile & 15) * 128;   // t-range base

    const int wave = tid >> 6;
    const int lane = tid & 63;
    const int wr = wave >> 1;            // row half (64 rows)
    const int wc = wave & 1;             // col half (64 cols)
    const int lcol = lane & 15;
    const int lq = lane >> 4;

    // A staging geometry: pass p: row r = p*32 + (tid>>3), float col (tid&7)*8
    const int arow = tid >> 3;           // 0..31
    const int afc = (tid & 7) * 8;       // 0..56
    const float* encbase = enc + ((size_t)(t0 + arow) * BB + b) * HH + afc;
    // B staging source (shorts): + ks*8192 per step; lane offset baked in
    const short* bsrc = W2p + nt * 65536 + (wave * 4) * 512 + lane * 8;

    f32x4 acc[4][4];
#pragma unroll
    for (int mt = 0; mt < 4; ++mt)
#pragma unroll
        for (int ns = 0; ns < 4; ++ns) acc[mt][ns] = (f32x4){0.f, 0.f, 0.f, 0.f};

    float4 rA0[8], rA1[8];

#define A_LOAD(RA, KS)                                                              \
    {                                                                               \
        _Pragma("unroll")                                                           \
        for (int p = 0; p < 4; ++p) {                                               \
            const float* src = encbase + (size_t)p * 32 * BB * HH + (KS) * 64;      \
            RA[p * 2]     = *reinterpret_cast<const float4*>(src);                  \
            RA[p * 2 + 1] = *reinterpret_cast<const float4*>(src + 4);              \
        }                                                                           \
    }

#define B_STAGE(KS, BUF)                                                            \
    {                                                                               \
        const short* s0 = bsrc + (KS) * 8192;                                       \
        _Pragma("unroll")                                                           \
        for (int c = 0; c < 4; ++c)                                                 \
            gload_lds16(s0 + c * 512, &Bs[BUF][(wave * 4 + c) * 512]);              \
    }

#define A_WRITE(RA, BUF)                                                            \
    {                                                                               \
        _Pragma("unroll")                                                           \
        for (int p = 0; p < 4; ++p) {                                               \
            const int r = p * 32 + arow;                                            \
            uint4 pk;                                                               \
            pk.x = cvt2(RA[p * 2].x, RA[p * 2].y);                                  \
            pk.y = cvt2(RA[p * 2].z, RA[p * 2].w);                                  \
            pk.z = cvt2(RA[p * 2 + 1].x, RA[p * 2 + 1].y);                          \
            pk.w = cvt2(RA[p * 2 + 1].z, RA[p * 2 + 1].w);                          \
            const int cs = afc ^ ((r & 7) << 3);                                    \
            *reinterpret_cast<uint4*>(&As[BUF][r * 64 + cs]) = pk;                  \
        }                                                                           \
    }

#define COMPUTE(BUF)                                                                \
    {                                                                               \
        __builtin_amdgcn_s_setprio(1);                                              \
        _Pragma("unroll")                                                           \
        for (int ksub = 0; ksub < 2; ++ksub) {                                      \
            const int kk = ksub * 32 + lq * 8;                                      \
            bf16x8 af[4], bfr[4];                                                   \
            _Pragma("unroll")                                                       \
            for (int mt = 0; mt < 4; ++mt) {                                        \
                const int r = wr * 64 + mt * 16 + lcol;                             \
                af[mt] = *reinterpret_cast<const bf16x8*>(                          \
                    &As[BUF][r * 64 + (kk ^ ((r & 7) << 3))]);                      \
            }                                                                       \
            _Pragma("unroll")                                                       \
            for (int ns = 0; ns < 4; ++ns) {                                        \
                const int j = wc * 64 + ns * 16 + lcol;                             \
                bfr[ns] = *reinterpret_cast<const bf16x8*>(                         \
                    &Bs[BUF][j * 64 + (kk ^ ((j & 7) << 3))]);                      \
            }                                                                       \
            _Pragma("unroll")                                                       \
            for (int mt = 0; mt < 4; ++mt)                                          \
                _Pragma("unroll")                                                   \
                for (int ns = 0; ns < 4; ++ns)                                      \
                    acc[mt][ns] = __builtin_amdgcn_mfma_f32_16x16x32_bf16(          \
                        af[mt], bfr[ns], acc[mt][ns], 0, 0, 0);                     \
        }                                                                           \
        __builtin_amdgcn_s_setprio(0);                                              \
    }

    // ---- prologue: loads for steps 0,1 first, then B stage 0, write A0.
    A_LOAD(rA0, 0);
    A_LOAD(rA1, 1);
    B_STAGE(0, 0);
    // compiler inserts vmcnt for rA0 use below (leaves rA1+B in flight)
    A_WRITE(rA0, 0);
    LGKM0_BAR();

    // ---- main K-loop: 8 steps, hand-unrolled x2, static ping-pong.
    // Iter s issues: A_LOAD(s+2) [8 vm] + B_STAGE(s+1) [4 vm] = 12.
    // Gate COMPUTE(s) on B_STAGE(s) (prev iter) with vmcnt(<this-iter issues>).
#pragma unroll
    for (int s2 = 0; s2 < 4; ++s2) {
        const int s = s2 * 2;
        // ---- even step s: compute buf0
        if (s + 2 < 8) A_LOAD(rA0, s + 2);
        B_STAGE(s + 1, 1);
        if (s2 < 3) { VMWAIT(12); } else { VMWAIT(4); }   // s=6 issues only 4
        COMPUTE(0);
        A_WRITE(rA1, 1);                    // data for step s+1 (loaded at s-1)
        LGKM0_BAR();
        // ---- odd step s+1: compute buf1
        if (s + 3 < 8) A_LOAD(rA1, s + 3);
        if (s + 2 < 8) B_STAGE(s + 2, 0);
        if (s2 < 3) { VMWAIT(12); } else { VMWAIT(0); }   // s=7 issues nothing
        COMPUTE(1);
        if (s + 2 < 8) {
            A_WRITE(rA0, 0);                // data for step s+2 (loaded at s)
            LGKM0_BAR();
        }
    }

    // ---- epilogue: tanh + v-dot, reduce over this block's 128 cols
    float part[4][4];
#pragma unroll
    for (int mt = 0; mt < 4; ++mt)
#pragma unroll
        for (int j = 0; j < 4; ++j) part[mt][j] = 0.0f;

#pragma unroll
    for (int ns = 0; ns < 4; ++ns) {
        const int o = nt * 128 + wc * 64 + ns * 16 + lcol;
        const float hbv = hb[b * 512 + o];
        const float vv = v[o];
#pragma unroll
        for (int mt = 0; mt < 4; ++mt)
#pragma unroll
            for (int j = 0; j < 4; ++j)
                part[mt][j] = fmaf(fast_tanh(acc[mt][ns][j] + hbv), vv, part[mt][j]);
    }

#pragma unroll
    for (int off = 1; off < 16; off <<= 1)
#pragma unroll
        for (int mt = 0; mt < 4; ++mt)
#pragma unroll
            for (int j = 0; j < 4; ++j)
                part[mt][j] += __shfl_xor(part[mt][j], off, 64);

    if (lcol == 0) {
#pragma unroll
        for (int mt = 0; mt < 4; ++mt)
#pragma unroll
            for (int j = 0; j < 4; ++j)
                s_red[wc][wr * 64 + mt * 16 + lq * 4 + j] = part[mt][j];
    }
    __syncthreads();

    if (tid < 128)
        scores_part[((size_t)nt * BB + b) * TT + t0 + tid] =
            s_red[0][tid] + s_red[1][tid];
}

// ---- Kernel 4: sum 4 N-tile partials + softmax over T per b
__global__ void softmax_kernel(const float* __restrict__ sp, float* __restrict__ out) {
    __shared__ float wred[4];
    __shared__ float wsum[4];
    const int b = blockIdx.x;
    const int tid = threadIdx.x;   // 256
    float vals[8];
    float mx = -1e30f;
#pragma unroll
    for (int i = 0; i < 8; ++i) {
        const int t = i * 256 + tid;
        const float s = sp[(size_t)b * TT + t] + sp[((size_t)BB + b) * TT + t] +
                        sp[((size_t)2 * BB + b) * TT + t] + sp[((size_t)3 * BB + b) * TT + t];
        vals[i] = s;
        mx = fmaxf(mx, s);
    }
#pragma unroll
    for (int off = 32; off; off >>= 1) mx = fmaxf(mx, __shfl_xor(mx, off, 64));
    if ((tid & 63) == 0) wred[tid >> 6] = mx;
    __syncthreads();
    mx = fmaxf(fmaxf(wred[0], wred[1]), fmaxf(wred[2], wred[3]));
    float s = 0.0f;
#pragma unroll
    for (int i = 0; i < 8; ++i) {
        vals[i] = __expf(vals[i] - mx);
        s += vals[i];
    }
#pragma unroll
    for (int off = 32; off; off >>= 1) s += __shfl_xor(s, off, 64);
    if ((tid & 63) == 0) wsum[tid >> 6] = s;
    __syncthreads();
    s = wsum[0] + wsum[1] + wsum[2] + wsum[3];
    const float inv = 1.0f / s;
#pragma unroll
    for (int i = 0; i < 8; ++i) out[b * TT + i * 256 + tid] = vals[i] * inv;
}

extern "C" void kernel_launch(void* const* d_in, const int* in_sizes, int n_in,
                              void* d_out, int out_size, void* d_ws, size_t ws_size,
                              hipStream_t stream) {
    const float* hidden = (const float*)d_in[0];   // (1,B,H)
    const float* enc    = (const float*)d_in[1];   // (T,B,H)
    const float* W      = (const float*)d_in[2];   // (H,2H)
    const float* b_attn = (const float*)d_in[3];   // (H,)
    const float* v      = (const float*)d_in[4];   // (H,)
    float* out = (float*)d_out;                    // (B,1,T)

    char* base = (char*)d_ws;
    short* W2p = (short*)base;                          // 512*512*2 = 524288 B
    float* hb  = (float*)(base + 524288);               // 32*512*4  =  65536 B
    float* sp  = (float*)(base + 524288 + 65536);       // 4*32*2048*4 = 1048576 B

    pack_w2_kernel<<<1024, 256, 0, stream>>>(W, W2p);
    hb_kernel<<<64, 256, 0, stream>>>(hidden, W, b_attn, hb);
    attn_main_kernel<<<2048, 256, 0, stream>>>(enc, W2p, hb, v, sp);
    softmax_kernel<<<32, 256, 0, stream>>>(sp, out);
}